// Round 6
// baseline (667.124 us; speedup 1.0000x reference)
//
#include <hip/hip_runtime.h>
#include <math.h>

#define B_ROWS 2048
#define D_K    2048
#define N_CLS  50257
#define BM     256
#define BN     256
#define BK     64
#define NT     (D_K / BK)       // 32 K-tiles
#define GM     8                // 2048/256 m-tiles
#define GN     197              // ceil(50257/256) n-tiles
#define N_PAD  (GN * BN)        // 50432
#define NWG    (GM * GN)        // 1576 = 8*197 (bijective XCD swizzle)

// LDS: buffer b at b*65536. A: [2 half][256 rows][32 cols] bf16 (32KB),
// B at +32768 same. Swizzle: 16B slot position p = content_slot ^ ((row>>1)&3).
#define BUFB   65536
#define HREG   16384            // bytes per kk-half region
#define STATS  131072

typedef __attribute__((ext_vector_type(8))) short          bf16x8;
typedef __attribute__((ext_vector_type(4))) float          f32x4;
typedef __attribute__((ext_vector_type(8))) unsigned short u16x8;

typedef __attribute__((address_space(1))) const void as1cv;
typedef __attribute__((address_space(3))) void       as3v;

__device__ __forceinline__ void glds16(const void* g, void* l) {
  __builtin_amdgcn_global_load_lds((as1cv*)g, (as3v*)l, 16, 0, 0);
}
__device__ __forceinline__ void bar() {
  __builtin_amdgcn_sched_barrier(0);
  __builtin_amdgcn_s_barrier();
  __builtin_amdgcn_sched_barrier(0);
}

__device__ __forceinline__ unsigned short f2bf(float x) {
  unsigned int u = __builtin_bit_cast(unsigned int, x);
  u += 0x7fffu + ((u >> 16) & 1u);   // RNE
  return (unsigned short)(u >> 16);
}

// ---------- fp32 -> bf16 (W zero-padded to N_PAD rows) ----------
__global__ void conv_w(const float* __restrict__ W, unsigned short* __restrict__ Wb) {
  const size_t NU = (size_t)N_PAD * D_K / 8;
  const size_t stride = (size_t)gridDim.x * blockDim.x;
  for (size_t u = (size_t)blockIdx.x * blockDim.x + threadIdx.x; u < NU; u += stride) {
    const size_t e = u * 8;
    u16x8 o = {0, 0, 0, 0, 0, 0, 0, 0};
    if ((e >> 11) < (size_t)N_CLS) {
      const float4 a = *(const float4*)(W + e);
      const float4 b = *(const float4*)(W + e + 4);
      o[0] = f2bf(a.x); o[1] = f2bf(a.y); o[2] = f2bf(a.z); o[3] = f2bf(a.w);
      o[4] = f2bf(b.x); o[5] = f2bf(b.y); o[6] = f2bf(b.z); o[7] = f2bf(b.w);
    }
    *(u16x8*)(Wb + e) = o;
  }
}

__global__ void conv_e(const float* __restrict__ E, unsigned short* __restrict__ Eb) {
  const size_t NU = (size_t)B_ROWS * D_K / 8;
  const size_t stride = (size_t)gridDim.x * blockDim.x;
  for (size_t u = (size_t)blockIdx.x * blockDim.x + threadIdx.x; u < NU; u += stride) {
    const size_t e = u * 8;
    const float4 a = *(const float4*)(E + e);
    const float4 b = *(const float4*)(E + e + 4);
    u16x8 o;
    o[0] = f2bf(a.x); o[1] = f2bf(a.y); o[2] = f2bf(a.z); o[3] = f2bf(a.w);
    o[4] = f2bf(b.x); o[5] = f2bf(b.y); o[6] = f2bf(b.z); o[7] = f2bf(b.w);
    *(u16x8*)(Eb + e) = o;
  }
}

// ---------- fused GEMM + per-tile row stats ----------
// 256x256, BK=64, 8 waves (2m x 4n), per-wave 128x64, acc[8][4].
// Register-pipelined: each quadrant's ds_reads issued one phase early;
// counted lgkmcnt/vmcnt (never 0 in steady state); 2 barriers per K-tile.
__global__ __launch_bounds__(512, 2) void gemm_ce(
    const unsigned short* __restrict__ Eb,
    const unsigned short* __restrict__ Wb,
    const int* __restrict__ labels,
    float* __restrict__ pm, float* __restrict__ ps, float* __restrict__ pt,
    float* __restrict__ ly)
{
  __shared__ __align__(16) char lds[STATS + 12288];
  float (*s_m)[4] = (float (*)[4])(lds + STATS);
  float (*s_s)[4] = (float (*)[4])(lds + STATS + 4096);
  float (*s_t)[4] = (float (*)[4])(lds + STATS + 8192);

  const int tid  = threadIdx.x;
  const int wid  = tid >> 6;
  const int lane = tid & 63;
  const int wm   = wid >> 2;       // 0..1 -> 128-row block
  const int wn   = wid & 3;        // 0..3 -> 64-col block
  const int l16  = lane & 15;
  const int lhi  = lane >> 4;

  // XCD-aware bijective swizzle (NWG = 8*197)
  const int bid     = blockIdx.x;
  const int logical = (bid & 7) * (NWG / 8) + (bid >> 3);
  const int n_tile  = logical / GM;
  const int m_tile  = logical % GM;

  // ---- staging: dest (region-linear) = q*8192 + wid*1024 + lane*16
  //      content slot = (lane&3) ^ ((lane>>3)&3)
  const int gk   = (((lane & 3) ^ ((lane >> 3) & 3)) * 8);
  const int srow = wid * 16 + (lane >> 2);
  const unsigned short* AgS = Eb + (size_t)(m_tile * BM + srow) * D_K + gk;
  const unsigned short* BgS = Wb + (size_t)(n_tile * BN + srow) * D_K + gk;
  const int ldoff = wid * 1024 + lane * 16;
  // +q -> +262144 elements (128 rows); +h -> +32 elements; +tile -> +64 elements

  // ---- fragment LDS offsets (within a kk-half region) ----
  const int sws  = (lhi ^ ((l16 >> 1) & 3)) << 4;
  const int aoff = (wm * 128 + l16) * 64 + sws;           // frag i: +i*1024; mh1: +4096
  const int boff = 32768 + (wn * 64 + l16) * 64 + sws;    // frag j: +j*1024

  f32x4 acc[8][4] = {};
  bf16x8 aA0, aA1, aA2, aA3, aB0, aB1, aB2, aB3;
  bf16x8 bA0, bA1, bA2, bA3, bB0, bB1, bB2, bB3;

#define MFMA4(IB, AV)                                                            \
  acc[IB][0] = __builtin_amdgcn_mfma_f32_16x16x32_bf16(AV, b0_, acc[IB][0], 0, 0, 0); \
  acc[IB][1] = __builtin_amdgcn_mfma_f32_16x16x32_bf16(AV, b1_, acc[IB][1], 0, 0, 0); \
  acc[IB][2] = __builtin_amdgcn_mfma_f32_16x16x32_bf16(AV, b2_, acc[IB][2], 0, 0, 0); \
  acc[IB][3] = __builtin_amdgcn_mfma_f32_16x16x32_bf16(AV, b3_, acc[IB][3], 0, 0, 0)

#define MFMA_Q(BASE, A0, A1, A2, A3, B0, B1, B2, B3)                             \
  do {                                                                           \
    bf16x8 b0_ = B0, b1_ = B1, b2_ = B2, b3_ = B3;                               \
    MFMA4(BASE + 0, A0); MFMA4(BASE + 1, A1);                                    \
    MFMA4(BASE + 2, A2); MFMA4(BASE + 3, A3);                                    \
  } while (0)

  // ---- prologue: stage tile 0 (order Ah0,Bh0,Ah1,Bh1); read Q0 operands ----
  {
    char* S = lds;
    glds16(AgS,               S + ldoff);
    glds16(AgS + 262144,      S + 8192 + ldoff);
    glds16(BgS,               S + 32768 + ldoff);
    glds16(BgS + 262144,      S + 32768 + 8192 + ldoff);
    glds16(AgS + 32,          S + HREG + ldoff);
    glds16(AgS + 262144 + 32, S + HREG + 8192 + ldoff);
    glds16(BgS + 32,          S + 32768 + HREG + ldoff);
    glds16(BgS + 262144 + 32, S + 32768 + HREG + 8192 + ldoff);
  }
  asm volatile("s_waitcnt vmcnt(4)" ::: "memory");   // h0(t0) landed
  bar();
  bA0 = *(const bf16x8*)(lds + boff);        bA1 = *(const bf16x8*)(lds + boff + 1024);
  bA2 = *(const bf16x8*)(lds + boff + 2048); bA3 = *(const bf16x8*)(lds + boff + 3072);
  aA0 = *(const bf16x8*)(lds + aoff);        aA1 = *(const bf16x8*)(lds + aoff + 1024);
  aA2 = *(const bf16x8*)(lds + aoff + 2048); aA3 = *(const bf16x8*)(lds + aoff + 3072);

  for (int t = 0; t < NT; ++t) {
    const char* Rb = lds + ((t & 1) << 16);
    char*       Sb = lds + (((t & 1) ^ 1) << 16);
    const bool  st   = (t < NT - 1);
    const bool  last = (t == NT - 1);
    const unsigned short* An = AgS + (size_t)(t + 1) * 64;
    const unsigned short* Bn = BgS + (size_t)(t + 1) * 64;

    // ===== P0: read Q1 A-frags; stage Ah0(t+1); MFMA Q0 =====
    aB0 = *(const bf16x8*)(Rb + aoff + 4096); aB1 = *(const bf16x8*)(Rb + aoff + 5120);
    aB2 = *(const bf16x8*)(Rb + aoff + 6144); aB3 = *(const bf16x8*)(Rb + aoff + 7168);
    if (st) { glds16(An, Sb + ldoff); glds16(An + 262144, Sb + 8192 + ldoff); }
    asm volatile("s_waitcnt lgkmcnt(4)" ::: "memory");   // Q0 regs ready
    __builtin_amdgcn_sched_barrier(0);
    __builtin_amdgcn_s_setprio(1);
    MFMA_Q(0, aA0, aA1, aA2, aA3, bA0, bA1, bA2, bA3);
    __builtin_amdgcn_s_setprio(0);

    // ===== P1: stage Bh0(t+1); mid-bar; read Q2 frags; MFMA Q1 =====
    if (st) { glds16(Bn, Sb + 32768 + ldoff); glds16(Bn + 262144, Sb + 32768 + 8192 + ldoff); }
    if (last) asm volatile("s_waitcnt vmcnt(0)" ::: "memory");
    else      asm volatile("s_waitcnt vmcnt(4)" ::: "memory");   // h1(t) landed
    bar();
    bB0 = *(const bf16x8*)(Rb + boff + HREG);        bB1 = *(const bf16x8*)(Rb + boff + HREG + 1024);
    bB2 = *(const bf16x8*)(Rb + boff + HREG + 2048); bB3 = *(const bf16x8*)(Rb + boff + HREG + 3072);
    aA0 = *(const bf16x8*)(Rb + aoff + HREG);        aA1 = *(const bf16x8*)(Rb + aoff + HREG + 1024);
    aA2 = *(const bf16x8*)(Rb + aoff + HREG + 2048); aA3 = *(const bf16x8*)(Rb + aoff + HREG + 3072);
    asm volatile("s_waitcnt lgkmcnt(8)" ::: "memory");   // Q1 A-frags ready
    __builtin_amdgcn_sched_barrier(0);
    __builtin_amdgcn_s_setprio(1);
    MFMA_Q(4, aB0, aB1, aB2, aB3, bA0, bA1, bA2, bA3);
    __builtin_amdgcn_s_setprio(0);

    // ===== P2: read Q3 A-frags; stage Ah1(t+1); MFMA Q2 =====
    aB0 = *(const bf16x8*)(Rb + aoff + HREG + 4096); aB1 = *(const bf16x8*)(Rb + aoff + HREG + 5120);
    aB2 = *(const bf16x8*)(Rb + aoff + HREG + 6144); aB3 = *(const bf16x8*)(Rb + aoff + HREG + 7168);
    if (st) { glds16(An + 32, Sb + HREG + ldoff); glds16(An + 262144 + 32, Sb + HREG + 8192 + ldoff); }
    asm volatile("s_waitcnt lgkmcnt(4)" ::: "memory");   // Q2 regs ready
    __builtin_amdgcn_sched_barrier(0);
    __builtin_amdgcn_s_setprio(1);
    MFMA_Q(0, aA0, aA1, aA2, aA3, bB0, bB1, bB2, bB3);
    __builtin_amdgcn_s_setprio(0);

    // ===== P3: stage Bh1(t+1); boundary bar; read Q0(t+1); MFMA Q3 =====
    if (st) { glds16(Bn + 32, Sb + 32768 + HREG + ldoff); glds16(Bn + 262144 + 32, Sb + 32768 + HREG + 8192 + ldoff); }
    if (!last) {
      asm volatile("s_waitcnt vmcnt(4)" ::: "memory");   // h0(t+1) landed
      bar();
      bA0 = *(const bf16x8*)(Sb + boff);        bA1 = *(const bf16x8*)(Sb + boff + 1024);
      bA2 = *(const bf16x8*)(Sb + boff + 2048); bA3 = *(const bf16x8*)(Sb + boff + 3072);
      aA0 = *(const bf16x8*)(Sb + aoff);        aA1 = *(const bf16x8*)(Sb + aoff + 1024);
      aA2 = *(const bf16x8*)(Sb + aoff + 2048); aA3 = *(const bf16x8*)(Sb + aoff + 3072);
      asm volatile("s_waitcnt lgkmcnt(8)" ::: "memory"); // Q3 A-frags ready
      __builtin_amdgcn_sched_barrier(0);
    } else {
      asm volatile("s_waitcnt lgkmcnt(0)" ::: "memory");
      __builtin_amdgcn_sched_barrier(0);
    }
    __builtin_amdgcn_s_setprio(1);
    MFMA_Q(4, aB0, aB1, aB2, aB3, bB0, bB1, bB2, bB3);
    __builtin_amdgcn_s_setprio(0);
  }
#undef MFMA_Q
#undef MFMA4

  // ---------- epilogue: per-row (max, sumexp, sum) + label gather ----------
  const int row_base = m_tile * BM;
  const int col_base = n_tile * BN + wn * 64;

#pragma unroll
  for (int i = 0; i < 8; ++i) {
#pragma unroll
    for (int r = 0; r < 4; ++r) {
      const int rt  = wm * 128 + i * 16 + lhi * 4 + r;
      const int row = row_base + rt;
      const int lab = labels[row];
      const int rel = lab - col_base - l16;
#pragma unroll
      for (int j = 0; j < 4; ++j) {
        if (rel == j * 16) ly[row] = acc[i][j][r];   // compile-time acc index
      }

      float mx = -INFINITY, smv = 0.f;
#pragma unroll
      for (int j = 0; j < 4; ++j) {
        const bool v = (col_base + j * 16 + l16) < N_CLS;
        const float x = acc[i][j][r];
        if (v) { mx = fmaxf(mx, x); smv += x; }
      }
#pragma unroll
      for (int d = 1; d < 16; d <<= 1) {
        mx = fmaxf(mx, __shfl_xor(mx, d));
        smv += __shfl_xor(smv, d);
      }
      float se = 0.f;
#pragma unroll
      for (int j = 0; j < 4; ++j) {
        const bool v = (col_base + j * 16 + l16) < N_CLS;
        if (v) se += __expf(acc[i][j][r] - mx);
      }
#pragma unroll
      for (int d = 1; d < 16; d <<= 1) se += __shfl_xor(se, d);

      if (l16 == 0) { s_m[rt][wn] = mx; s_s[rt][wn] = se; s_t[rt][wn] = smv; }
    }
  }
  __syncthreads();
  if (tid < BM) {
    float M = -INFINITY;
#pragma unroll
    for (int g = 0; g < 4; ++g) M = fmaxf(M, s_m[tid][g]);
    float S = 0.f, T = 0.f;
#pragma unroll
    for (int g = 0; g < 4; ++g) {
      S += s_s[tid][g] * __expf(s_m[tid][g] - M);
      T += s_t[tid][g];
    }
    const size_t o = (size_t)n_tile * B_ROWS + row_base + tid;
    pm[o] = M; ps[o] = S; pt[o] = T;
  }
}

// ---------- final combine: GN partials per row -> loss ----------
__global__ void ce_reduce(const float* __restrict__ pm, const float* __restrict__ ps,
                          const float* __restrict__ pt, const float* __restrict__ ly,
                          float* __restrict__ out)
{
  const int tid = threadIdx.x;
  const int row = blockIdx.x * blockDim.x + tid;
  float M = -INFINITY, S = 0.f, T = 0.f;
  for (int nt = 0; nt < GN; ++nt) {
    const size_t o = (size_t)nt * B_ROWS + row;
    const float m = pm[o], s = ps[o], t = pt[o];
    const float Mn = fmaxf(M, m);
    S = S * __expf(M - Mn) + s * __expf(m - Mn);
    M = Mn;
    T += t;
  }
  const float lse = M + logf(S);
  float per = lse - 0.9f * ly[row] - 0.1f * (T * (1.0f / (float)N_CLS));
#pragma unroll
  for (int d = 1; d < 64; d <<= 1) per += __shfl_xor(per, d);
  __shared__ float red[4];
  if ((tid & 63) == 0) red[tid >> 6] = per;
  __syncthreads();
  if (tid == 0)
    atomicAdd(out, (red[0] + red[1] + red[2] + red[3]) * (1.0f / B_ROWS));
}

extern "C" void kernel_launch(void* const* d_in, const int* in_sizes, int n_in,
                              void* d_out, int out_size, void* d_ws, size_t ws_size,
                              hipStream_t stream)
{
  const float* E      = (const float*)d_in[0];
  const int*   labels = (const int*)  d_in[1];
  const float* W      = (const float*)d_in[2];
  float* out = (float*)d_out;

  char* ws = (char*)d_ws;
  unsigned short* Wb = (unsigned short*)ws;
  size_t off = (size_t)N_PAD * D_K * 2;            // 206,569,472 B
  unsigned short* Eb = (unsigned short*)(ws + off);
  off += (size_t)B_ROWS * D_K * 2;                 // + 8,388,608 B
  float* pm = (float*)(ws + off); off += (size_t)GN * B_ROWS * 4;
  float* ps = (float*)(ws + off); off += (size_t)GN * B_ROWS * 4;
  float* pt = (float*)(ws + off); off += (size_t)GN * B_ROWS * 4;
  float* ly = (float*)(ws + off);                  // total ~220 MB

  hipMemsetAsync(d_out, 0, sizeof(float), stream);
  conv_w<<<dim3(2048), dim3(256), 0, stream>>>(W, Wb);
  conv_e<<<dim3(512),  dim3(256), 0, stream>>>(E, Eb);
  gemm_ce<<<dim3(NWG), dim3(512), 0, stream>>>(Eb, Wb, labels, pm, ps, pt, ly);
  ce_reduce<<<dim3(B_ROWS / 256), dim3(256), 0, stream>>>(pm, ps, pt, ly, out);
}

// Round 7
// 573.489 us; speedup vs baseline: 1.1633x; 1.1633x over previous
//
#include <hip/hip_runtime.h>
#include <hip/hip_fp8.h>
#include <math.h>

#define B_ROWS 2048
#define D_K    2048
#define N_CLS  50257
#define BM     256
#define BN     256
#define BK     64
#define NT     (D_K / BK)       // 32 K-tiles
#define GM     8                // 2048/256 m-tiles
#define GN     197              // ceil(50257/256) n-tiles
#define N_PAD  (GN * BN)        // 50432
#define NWG    (GM * GN)        // 1576 = 8*197 (bijective XCD swizzle)

// LDS: 3 buffers x 32KB. Per buffer: A [256 rows][64 B] fp8 at +0,
// B [256 cols][64 B] at +16384. 16B-slot swizzle: p = s ^ ((row>>1)&3).
#define ABYTES 16384
#define BUFB   32768
#define STATS  98304

typedef __attribute__((ext_vector_type(4)))  int   i32x4;
typedef __attribute__((ext_vector_type(8)))  int   i32x8;
typedef __attribute__((ext_vector_type(16))) float f32x16;

typedef __attribute__((address_space(1))) const void as1cv;
typedef __attribute__((address_space(3))) void       as3v;

__device__ __forceinline__ void glds16(const void* g, void* l) {
  __builtin_amdgcn_global_load_lds((as1cv*)g, (as3v*)l, 16, 0, 0);
}
__device__ __forceinline__ void bar() {
  __builtin_amdgcn_sched_barrier(0);
  __builtin_amdgcn_s_barrier();
  __builtin_amdgcn_sched_barrier(0);
}

__device__ __forceinline__ unsigned char f2q(float x) {
  __hip_fp8_e4m3 q(x);
  return *reinterpret_cast<unsigned char*>(&q);
}

// ---------- fp32 -> fp8 e4m3 (W scaled by 128, zero-padded to N_PAD rows) ----------
__global__ void conv_w_q(const float* __restrict__ W, unsigned char* __restrict__ Wq) {
  const size_t NU = (size_t)N_PAD * D_K / 8;
  const size_t stride = (size_t)gridDim.x * blockDim.x;
  for (size_t u = (size_t)blockIdx.x * blockDim.x + threadIdx.x; u < NU; u += stride) {
    const size_t e = u * 8;
    unsigned long long pk = 0ull;
    if ((e >> 11) < (size_t)N_CLS) {
      const float4 a = *(const float4*)(W + e);
      const float4 b = *(const float4*)(W + e + 4);
      const float v[8] = {a.x, a.y, a.z, a.w, b.x, b.y, b.z, b.w};
#pragma unroll
      for (int i = 0; i < 8; ++i)
        pk |= (unsigned long long)f2q(v[i] * 128.0f) << (8 * i);
    }
    *(unsigned long long*)(Wq + e) = pk;
  }
}

__global__ void conv_e_q(const float* __restrict__ E, unsigned char* __restrict__ Eq) {
  const size_t NU = (size_t)B_ROWS * D_K / 8;
  const size_t stride = (size_t)gridDim.x * blockDim.x;
  for (size_t u = (size_t)blockIdx.x * blockDim.x + threadIdx.x; u < NU; u += stride) {
    const size_t e = u * 8;
    const float4 a = *(const float4*)(E + e);
    const float4 b = *(const float4*)(E + e + 4);
    const float v[8] = {a.x, a.y, a.z, a.w, b.x, b.y, b.z, b.w};
    unsigned long long pk = 0ull;
#pragma unroll
    for (int i = 0; i < 8; ++i)
      pk |= (unsigned long long)f2q(v[i]) << (8 * i);
    *(unsigned long long*)(Eq + e) = pk;
  }
}

// ---------- fused MX-fp8 GEMM + per-tile row stats ----------
// 256x256 tile, BK=64, 8 waves (2m x 4n), per-wave 128x64 via 8x mfma 32x32x64.
// Uniform MX scales = 1.0 (0x7F per byte); W pre-scaled x128, acc scaled /128.
__global__ __launch_bounds__(512, 2) void gemm_ce(
    const unsigned char* __restrict__ Eq,
    const unsigned char* __restrict__ Wq,
    const int* __restrict__ labels,
    float* __restrict__ pm, float* __restrict__ ps, float* __restrict__ pt,
    float* __restrict__ ly)
{
  __shared__ __align__(16) char lds[STATS + 12288];
  float (*s_m)[4] = (float (*)[4])(lds + STATS);
  float (*s_s)[4] = (float (*)[4])(lds + STATS + 4096);
  float (*s_t)[4] = (float (*)[4])(lds + STATS + 8192);

  const int tid  = threadIdx.x;
  const int wid  = tid >> 6;
  const int lane = tid & 63;
  const int wm   = wid >> 2;       // 0..1 -> 128-row block
  const int wn   = wid & 3;        // 0..3 -> 64-col block
  const int l31  = lane & 31;
  const int lh   = lane >> 5;

  // XCD-aware bijective swizzle (NWG = 8*197)
  const int bid     = blockIdx.x;
  const int logical = (bid & 7) * (NWG / 8) + (bid >> 3);
  const int n_tile  = logical / GM;
  const int m_tile  = logical % GM;

  // ---- staging: dest byte (per glds16 q) = q*8192 + wid*1024 + lane*16
  //      -> row = q*128 + wid*16 + (lane>>2), dest slot16 = lane&3
  //      content slot = (lane&3) ^ ((row>>1)&3) = (lane&3) ^ ((lane>>3)&3)
  const int srow = wid * 16 + (lane >> 2);
  const int ssw  = (((lane & 3) ^ ((lane >> 3) & 3)) << 4);
  const unsigned char* Ag = Eq + (size_t)(m_tile * BM + srow) * D_K + ssw;
  const unsigned char* Bg = Wq + (size_t)(n_tile * BN + srow) * D_K + ssw;
  const int sdst = wid * 1024;
  // +q -> +128 rows = +262144 bytes global; +tile -> +64 bytes

  // ---- fragment LDS offsets: lane reads row = base + l31, 32 k-bytes at
  //      (lh*32); two b128 at slots p = (lh*2+rd) ^ ((l31>>1)&3)
  const int rmsk = (l31 >> 1) & 3;
  const int lk2  = lh * 2;
  int aoff[4][2], boff[2][2];
#pragma unroll
  for (int fi = 0; fi < 4; ++fi)
#pragma unroll
    for (int rd = 0; rd < 2; ++rd)
      aoff[fi][rd] = (wm * 128 + fi * 32 + l31) * 64 + (((lk2 + rd) ^ rmsk) << 4);
#pragma unroll
  for (int fj = 0; fj < 2; ++fj)
#pragma unroll
    for (int rd = 0; rd < 2; ++rd)
      boff[fj][rd] = ABYTES + (wn * 64 + fj * 32 + l31) * 64 + (((lk2 + rd) ^ rmsk) << 4);

  f32x16 acc[4][2] = {};

#define STAGE(BUF, TT)                                                      \
  do {                                                                      \
    const unsigned char* _a = Ag + (size_t)(TT) * BK;                       \
    const unsigned char* _b = Bg + (size_t)(TT) * BK;                       \
    char* _d = lds + (BUF) * BUFB + sdst;                                   \
    glds16(_a,          _d);                                                \
    glds16(_a + 262144, _d + 8192);                                         \
    glds16(_b,          _d + ABYTES);                                       \
    glds16(_b + 262144, _d + ABYTES + 8192);                                \
  } while (0)

  // ---- prologue: stage tiles 0,1 into bufs 0,1 ----
  STAGE(0, 0);
  STAGE(1, 1);

  int c0 = 0, c1 = 1, c2 = 2;
  union FR { i32x8 v; i32x4 h[2]; };

  for (int t = 0; t < NT; ++t) {
    const char* Rb = lds + c0 * BUFB;

    if (t == NT - 1) asm volatile("s_waitcnt vmcnt(0)" ::: "memory");
    else             asm volatile("s_waitcnt vmcnt(4)" ::: "memory");
    bar();

    FR fa[4], fb[2];
#pragma unroll
    for (int fj = 0; fj < 2; ++fj) {
      fb[fj].h[0] = *(const i32x4*)(Rb + boff[fj][0]);
      fb[fj].h[1] = *(const i32x4*)(Rb + boff[fj][1]);
    }
#pragma unroll
    for (int fi = 0; fi < 4; ++fi) {
      fa[fi].h[0] = *(const i32x4*)(Rb + aoff[fi][0]);
      fa[fi].h[1] = *(const i32x4*)(Rb + aoff[fi][1]);
    }
    if (t < NT - 2) STAGE(c2, t + 2);

    asm volatile("s_waitcnt lgkmcnt(0)" ::: "memory");
    __builtin_amdgcn_sched_barrier(0);
    __builtin_amdgcn_s_setprio(1);
#pragma unroll
    for (int fi = 0; fi < 4; ++fi)
#pragma unroll
      for (int fj = 0; fj < 2; ++fj)
        acc[fi][fj] = __builtin_amdgcn_mfma_scale_f32_32x32x64_f8f6f4(
            fa[fi].v, fb[fj].v, acc[fi][fj], 0, 0,
            0, 0x7F7F7F7F, 0, 0x7F7F7F7F);
    __builtin_amdgcn_s_setprio(0);
    bar();

    const int tmp = c0; c0 = c1; c1 = c2; c2 = tmp;
  }
#undef STAGE

  // ---------- epilogue: per-row (max, sumexp, sum) + label gather ----------
  // C/D 32x32: col = lane&31, row = (reg&3) + 8*(reg>>2) + 4*(lane>>5)
  const float inv = 0.0078125f;   // 1/128 (undo W pre-scale)
  const int colb = n_tile * BN + wn * 64;
  const int c0_  = colb + l31;
  const int c1_  = c0_ + 32;
  const bool ok0 = c0_ < N_CLS;
  const bool ok1 = c1_ < N_CLS;

#pragma unroll
  for (int fi = 0; fi < 4; ++fi) {
#pragma unroll
    for (int reg = 0; reg < 16; ++reg) {
      const int rt  = wm * 128 + fi * 32 + (reg & 3) + 8 * (reg >> 2) + 4 * lh;
      const int row = m_tile * BM + rt;
      const float v0 = acc[fi][0][reg] * inv;
      const float v1 = acc[fi][1][reg] * inv;
      const int lab = labels[row];
      if (lab == c0_) ly[row] = v0;
      if (lab == c1_) ly[row] = v1;

      float mx = fmaxf(ok0 ? v0 : -INFINITY, ok1 ? v1 : -INFINITY);
      float sm = (ok0 ? v0 : 0.f) + (ok1 ? v1 : 0.f);
#pragma unroll
      for (int d = 1; d < 32; d <<= 1) {
        mx = fmaxf(mx, __shfl_xor(mx, d));
        sm += __shfl_xor(sm, d);
      }
      float se = (ok0 ? __expf(v0 - mx) : 0.f) + (ok1 ? __expf(v1 - mx) : 0.f);
#pragma unroll
      for (int d = 1; d < 32; d <<= 1) se += __shfl_xor(se, d);

      if (l31 == 0) { s_m[rt][wn] = mx; s_s[rt][wn] = se; s_t[rt][wn] = sm; }
    }
  }
  __syncthreads();
  if (tid < BM) {
    float M = -INFINITY;
#pragma unroll
    for (int g = 0; g < 4; ++g) M = fmaxf(M, s_m[tid][g]);
    float S = 0.f, T = 0.f;
#pragma unroll
    for (int g = 0; g < 4; ++g) {
      S += s_s[tid][g] * __expf(s_m[tid][g] - M);
      T += s_t[tid][g];
    }
    const size_t o = (size_t)n_tile * B_ROWS + m_tile * BM + tid;
    pm[o] = M; ps[o] = S; pt[o] = T;
  }
}

// ---------- final combine: GN partials per row -> loss ----------
__global__ void ce_reduce(const float* __restrict__ pm, const float* __restrict__ ps,
                          const float* __restrict__ pt, const float* __restrict__ ly,
                          float* __restrict__ out)
{
  const int tid = threadIdx.x;
  const int row = blockIdx.x * blockDim.x + tid;
  float M = -INFINITY, S = 0.f, T = 0.f;
  for (int nt = 0; nt < GN; ++nt) {
    const size_t o = (size_t)nt * B_ROWS + row;
    const float m = pm[o], s = ps[o], t = pt[o];
    const float Mn = fmaxf(M, m);
    S = S * __expf(M - Mn) + s * __expf(m - Mn);
    M = Mn;
    T += t;
  }
  const float lse = M + logf(S);
  float per = lse - 0.9f * ly[row] - 0.1f * (T * (1.0f / (float)N_CLS));
#pragma unroll
  for (int d = 1; d < 64; d <<= 1) per += __shfl_xor(per, d);
  __shared__ float red[4];
  if ((tid & 63) == 0) red[tid >> 6] = per;
  __syncthreads();
  if (tid == 0)
    atomicAdd(out, (red[0] + red[1] + red[2] + red[3]) * (1.0f / B_ROWS));
}

extern "C" void kernel_launch(void* const* d_in, const int* in_sizes, int n_in,
                              void* d_out, int out_size, void* d_ws, size_t ws_size,
                              hipStream_t stream)
{
  const float* E      = (const float*)d_in[0];
  const int*   labels = (const int*)  d_in[1];
  const float* W      = (const float*)d_in[2];
  float* out = (float*)d_out;

  char* ws = (char*)d_ws;
  unsigned char* Wq = (unsigned char*)ws;
  size_t off = (size_t)N_PAD * D_K;                // 103,284,736 B
  unsigned char* Eq = (unsigned char*)(ws + off);
  off += (size_t)B_ROWS * D_K;                     // + 4,194,304 B
  float* pm = (float*)(ws + off); off += (size_t)GN * B_ROWS * 4;
  float* ps = (float*)(ws + off); off += (size_t)GN * B_ROWS * 4;
  float* pt = (float*)(ws + off); off += (size_t)GN * B_ROWS * 4;
  float* ly = (float*)(ws + off);                  // total ~112 MB

  hipMemsetAsync(d_out, 0, sizeof(float), stream);
  conv_w_q<<<dim3(2048), dim3(256), 0, stream>>>(W, Wq);
  conv_e_q<<<dim3(512),  dim3(256), 0, stream>>>(E, Eq);
  gemm_ce<<<dim3(NWG), dim3(512), 0, stream>>>(Eq, Wq, labels, pm, ps, pt, ly);
  ce_reduce<<<dim3(B_ROWS / 256), dim3(256), 0, stream>>>(pm, ps, pt, ly, out);
}